// Round 7
// baseline (167.119 us; speedup 1.0000x reference)
//
#include <hip/hip_runtime.h>

typedef __bf16 bf16x8 __attribute__((ext_vector_type(8)));
typedef float f32x4 __attribute__((ext_vector_type(4)));
typedef unsigned short u16;
typedef unsigned short u16x4 __attribute__((ext_vector_type(4)));
typedef unsigned short u16x8 __attribute__((ext_vector_type(8)));

#define MFMA16(a, b, c) __builtin_amdgcn_mfma_f32_16x16x32_bf16(a, b, c, 0, 0, 0)

__device__ __forceinline__ u16 f2bf(float f) {
    unsigned u = __builtin_bit_cast(unsigned, f);
    u += 0x7fffu + ((u >> 16) & 1u);   // RNE
    return (u16)(u >> 16);
}

__device__ __forceinline__ bf16x8 ld_frag(const u16* p) {
    u16x8 v = *(const u16x8*)p;
    return __builtin_bit_cast(bf16x8, v);
}

__device__ __forceinline__ u16x8 pack8(float4 a, float4 b) {
    u16x8 o = { f2bf(a.x), f2bf(a.y), f2bf(a.z), f2bf(a.w),
                f2bf(b.x), f2bf(b.y), f2bf(b.z), f2bf(b.w) };
    return o;
}

// 8x fp32 -> bf16x8 (scalar RNE bit-twiddle; trivially-copyable types only)
__device__ __forceinline__ bf16x8 cvt8(float4 a, float4 b) {
    return __builtin_bit_cast(bf16x8, pack8(a, b));
}

// ---------------------------------------------------------------------------
// wcvt: Wq|Wk|Wv fp32 -> Wb bf16, N-fused B-fragment order.
// Wb u16 off = ((c*48 + n16*2 + ks)*64 + lane)*8 ;  lane=(quad,l16)
// element  = Wcat[n16*16 + l16][c*64 + ks*32 + quad*8 + j],  Wcat=[Wq;Wk;Wv]
// ---------------------------------------------------------------------------
__global__ __launch_bounds__(256) void wcvt(
    const float* __restrict__ Wq, const float* __restrict__ Wk,
    const float* __restrict__ Wv, u16* __restrict__ Wb)
{
    int g = blockIdx.x * 256 + threadIdx.x;   // 49152
    int l = g & 63;
    int rest = g >> 6;
    int f = rest % 48, c = rest / 48;
    int n16 = f >> 1, ks = f & 1;
    int nrow = n16 * 16 + (l & 15);           // 0..383
    int nt = nrow >> 7, r = nrow & 127;
    int k = c * 64 + ks * 32 + (l >> 4) * 8;
    const float* W = (nt == 0 ? Wq : nt == 1 ? Wk : Wv) + (size_t)r * 1024 + k;
    float4 a = *(const float4*)(W);
    float4 b = *(const float4*)(W + 4);
    *(u16x8*)(Wb + (size_t)g * 8) = pack8(a, b);
}

// ---------------------------------------------------------------------------
// qkv_fused: q|k|v = x @ W^T + b.  grid 512 (m-tiles of 32), x read ONCE.
// NO LDS, NO BARRIERS in the K-loop: A-frags loaded per-lane from x (fp32,
// L1/L2-reused 4x in-block) + in-reg cvt; B-frags from frag-order Wb (L2-hot).
// x prefetched 1 chunk ahead in registers. Wave-tile 32m x 96n, acc 2x6.
// Epilogue (only LDS use): q natural [s][d]; k,v transposed [d][t].
// ---------------------------------------------------------------------------
__global__ __launch_bounds__(256, 2) void qkv_fused(
    const float* __restrict__ x, const u16* __restrict__ Wb,
    const float* __restrict__ bq, const float* __restrict__ bk,
    const float* __restrict__ bv,
    u16* __restrict__ qo, u16* __restrict__ kT, u16* __restrict__ vT)
{
    // epilogue-only LDS: Eq[32][136] | Ek[128][40] | Ev[128][40]
    __shared__ __align__(16) u16 smem[14592];

    const int m0 = blockIdx.x * 32;
    const int tid = threadIdx.x, lane = tid & 63, w = tid >> 6;
    const int quad = lane >> 4, l16 = lane & 15;
    const int nb0 = w * 6;   // wave's first n16 (6 per wave = 96 cols)

    // per-lane A source pointers, frag f = m16*2 + ks
    const float* xA[4];
    #pragma unroll
    for (int m16 = 0; m16 < 2; ++m16)
        #pragma unroll
        for (int ks = 0; ks < 2; ++ks)
            xA[m16 * 2 + ks] =
                x + (size_t)(m0 + m16 * 16 + l16) * 1024 + ks * 32 + quad * 8;

    const u16* wb = Wb + lane * 8;

    f32x4 acc[2][6] = {};

    // prologue: chunk-0 x into regs
    float4 xr[8];
    #pragma unroll
    for (int f = 0; f < 4; ++f) {
        xr[f * 2]     = *(const float4*)(xA[f]);
        xr[f * 2 + 1] = *(const float4*)(xA[f] + 4);
    }

    #pragma unroll
    for (int c = 0; c < 16; ++c) {
        // B frags for this chunk (L2-hot; consumed a few MFMAs later)
        u16x8 braw[12];
        #pragma unroll
        for (int ni = 0; ni < 6; ++ni)
            #pragma unroll
            for (int ks = 0; ks < 2; ++ks)
                braw[ni * 2 + ks] = *(const u16x8*)(
                    wb + (size_t)((c * 48 + (nb0 + ni) * 2 + ks) * 64) * 8);

        // prefetch next chunk's x (HBM latency hidden behind MFMA block)
        float4 xn[8];
        if (c < 15) {
            #pragma unroll
            for (int f = 0; f < 4; ++f) {
                xn[f * 2]     = *(const float4*)(xA[f] + (c + 1) * 64);
                xn[f * 2 + 1] = *(const float4*)(xA[f] + (c + 1) * 64 + 4);
            }
        }

        // cvt current x regs -> A frags
        bf16x8 af[4];
        #pragma unroll
        for (int f = 0; f < 4; ++f)
            af[f] = cvt8(xr[f * 2], xr[f * 2 + 1]);

        #pragma unroll
        for (int ks = 0; ks < 2; ++ks)
            #pragma unroll
            for (int mi = 0; mi < 2; ++mi)
                #pragma unroll
                for (int ni = 0; ni < 6; ++ni)
                    acc[mi][ni] = MFMA16(af[mi * 2 + ks],
                                         __builtin_bit_cast(bf16x8, braw[ni * 2 + ks]),
                                         acc[mi][ni]);

        if (c < 15) {
            #pragma unroll
            for (int j = 0; j < 8; ++j) xr[j] = xn[j];
        }
    }

    // ---------------- epilogue (only LDS + only barrier) ----------------
    u16* Eq = smem;          // 32 x 136
    u16* Ek = smem + 4352;   // 128 x 40
    u16* Ev = smem + 9472;   // 128 x 40

    #pragma unroll
    for (int ni = 0; ni < 6; ++ni) {
        int n16g = nb0 + ni;            // 0..23
        int sel = n16g >> 3;            // 0=q 1=k 2=v (wave-uniform)
        int col = (n16g & 7) * 16 + l16;
        const float* bias = sel == 0 ? bq : (sel == 1 ? bk : bv);
        float bb = bias[col];
        if (sel == 0) {
            #pragma unroll
            for (int mi = 0; mi < 2; ++mi)
                #pragma unroll
                for (int r = 0; r < 4; ++r)
                    Eq[(mi * 16 + quad * 4 + r) * 136 + col] =
                        f2bf(acc[mi][ni][r] + bb);
        } else {
            u16* E = (sel == 1) ? Ek : Ev;
            #pragma unroll
            for (int mi = 0; mi < 2; ++mi) {
                u16x4 v4 = { f2bf(acc[mi][ni][0] + bb), f2bf(acc[mi][ni][1] + bb),
                             f2bf(acc[mi][ni][2] + bb), f2bf(acc[mi][ni][3] + bb) };
                *(u16x4*)&E[col * 40 + mi * 16 + quad * 4] = v4;
            }
        }
    }
    __syncthreads();

    // q: 32 rows x 128 d, coalesced
    #pragma unroll
    for (int i = 0; i < 2; ++i) {
        int idx = tid + i * 256;
        int row = idx >> 4, d8 = (idx & 15) * 8;
        *(u16x8*)(qo + (size_t)(m0 + row) * 128 + d8) = *(u16x8*)&Eq[row * 136 + d8];
    }
    // kT/vT: 128 d-rows x 32 t each
    #pragma unroll
    for (int i = 0; i < 2; ++i) {
        int idx = tid + i * 256;
        int d = idx >> 2, t8 = (idx & 3) * 8;
        *(u16x8*)(kT + (size_t)d * 16384 + m0 + t8) = *(u16x8*)&Ek[d * 40 + t8];
        *(u16x8*)(vT + (size_t)d * 16384 + m0 + t8) = *(u16x8*)&Ev[d * 40 + t8];
    }
}

// ---------------------------------------------------------------------------
// kt_v: partial T[e][d] = sum_t vT[e][t]*kT[d][t] over a 128-t chunk.
// grid (32,4), 512 threads / 8 waves (wave 64e x 32d).
// ---------------------------------------------------------------------------
__global__ __launch_bounds__(512) void kt_v(
    const u16* __restrict__ kT, const u16* __restrict__ vT,
    float* __restrict__ part)
{
    __shared__ __align__(16) u16 vL[128 * 136];
    __shared__ __align__(16) u16 kL[128 * 136];

    const int c = blockIdx.x, b = blockIdx.y;
    const size_t g0 = (size_t)b * 4096 + c * 128;
    const int tid = threadIdx.x, lane = tid & 63, w = tid >> 6;
    const int quad = lane >> 4, l16 = lane & 15;
    const int we = (w >> 2) * 64, wd = (w & 3) * 32;

    #pragma unroll
    for (int i = 0; i < 4; ++i) {
        int idx = tid + i * 512;
        int e = idx >> 4, t8 = (idx & 15) * 8;
        *(u16x8*)&vL[e * 136 + t8] = *(const u16x8*)(vT + (size_t)e * 16384 + g0 + t8);
        *(u16x8*)&kL[e * 136 + t8] = *(const u16x8*)(kT + (size_t)e * 16384 + g0 + t8);
    }
    __syncthreads();

    f32x4 acc[4][2] = {};
    #pragma unroll
    for (int ks = 0; ks < 4; ++ks) {
        bf16x8 af[4], bfr[2];
        #pragma unroll
        for (int mi = 0; mi < 4; ++mi)
            af[mi] = ld_frag(&vL[(we + mi * 16 + l16) * 136 + ks * 32 + quad * 8]);
        #pragma unroll
        for (int ni = 0; ni < 2; ++ni)
            bfr[ni] = ld_frag(&kL[(wd + ni * 16 + l16) * 136 + ks * 32 + quad * 8]);
        #pragma unroll
        for (int mi = 0; mi < 4; ++mi)
            #pragma unroll
            for (int ni = 0; ni < 2; ++ni)
                acc[mi][ni] = MFMA16(af[mi], bfr[ni], acc[mi][ni]);
    }

    float* dst = part + (size_t)(b * 32 + c) * 16384;
    #pragma unroll
    for (int mi = 0; mi < 4; ++mi)
        #pragma unroll
        for (int ni = 0; ni < 2; ++ni)
            #pragma unroll
            for (int r = 0; r < 4; ++r)
                dst[(we + mi * 16 + quad * 4 + r) * 128 + (wd + ni * 16 + l16)] =
                    acc[mi][ni][r];
}

// ---------------------------------------------------------------------------
// reduceT: 32 fp32 partials -> T bf16 [4][128][128], scale folded in.
// ---------------------------------------------------------------------------
__global__ __launch_bounds__(256) void reduceT(
    const float* __restrict__ part, u16* __restrict__ T)
{
    int gid = blockIdx.x * 256 + threadIdx.x;   // 0..65535
    int b = gid >> 14, idx = gid & 16383;
    const float* p = part + (size_t)b * 32 * 16384 + idx;
    float s = 0.f;
    #pragma unroll
    for (int c = 0; c < 32; ++c) s += p[(size_t)c * 16384];
    T[gid] = f2bf(s * 0.088388347648318447f);   // 128^-0.5
}

// ---------------------------------------------------------------------------
// out_gemm: outT-form — C[e][s], A=T[e][d], B=q[s][d] (both d-contig).
// C/D layout gives out[s][e] as contiguous f32x4 -> full-line stores.
// grid 512 (32-s tiles, 2 blocks/CU), 4 waves: wave 64e x 16s.
// ---------------------------------------------------------------------------
__global__ __launch_bounds__(256) void out_gemm(
    const u16* __restrict__ qo, const u16* __restrict__ T,
    float* __restrict__ out)
{
    __shared__ __align__(16) u16 tL[128 * 136];
    __shared__ __align__(16) u16 qL[32 * 136];

    const int s0 = blockIdx.x * 32;
    const int b  = s0 >> 12;
    const int tid = threadIdx.x, lane = tid & 63, w = tid >> 6;
    const int quad = lane >> 4, l16 = lane & 15;
    const int we = (w >> 1) * 64, wsx = (w & 1) * 16;

    #pragma unroll
    for (int i = 0; i < 8; ++i) {
        int idx = tid + i * 256;
        int e = idx >> 4, d8 = (idx & 15) * 8;
        *(u16x8*)&tL[e * 136 + d8] = *(const u16x8*)(T + (size_t)b * 16384 + e * 128 + d8);
    }
    #pragma unroll
    for (int i = 0; i < 2; ++i) {
        int idx = tid + i * 256;
        int sr = idx >> 4, d8 = (idx & 15) * 8;
        *(u16x8*)&qL[sr * 136 + d8] = *(const u16x8*)(qo + (size_t)(s0 + sr) * 128 + d8);
    }
    __syncthreads();

    f32x4 acc[4] = {};
    #pragma unroll
    for (int ks = 0; ks < 4; ++ks) {
        bf16x8 bfr = ld_frag(&qL[(wsx + l16) * 136 + ks * 32 + quad * 8]);
        #pragma unroll
        for (int mi = 0; mi < 4; ++mi) {
            bf16x8 af = ld_frag(&tL[(we + mi * 16 + l16) * 136 + ks * 32 + quad * 8]);
            acc[mi] = MFMA16(af, bfr, acc[mi]);
        }
    }

    #pragma unroll
    for (int mi = 0; mi < 4; ++mi) {
        int s = s0 + wsx + l16;
        int e0 = we + mi * 16 + quad * 4;
        *(f32x4*)(out + (size_t)s * 128 + e0) = acc[mi];
    }
}

// ---------------------------------------------------------------------------
extern "C" void kernel_launch(void* const* d_in, const int* in_sizes, int n_in,
                              void* d_out, int out_size, void* d_ws, size_t ws_size,
                              hipStream_t stream)
{
    const float* x  = (const float*)d_in[0];
    const float* Wq = (const float*)d_in[1];
    const float* bq = (const float*)d_in[2];
    const float* Wk = (const float*)d_in[3];
    const float* bk = (const float*)d_in[4];
    const float* Wv = (const float*)d_in[5];
    const float* bv = (const float*)d_in[6];
    float* out = (float*)d_out;

    char* ws = (char*)d_ws;
    u16*   qo   = (u16*)(ws);                          //  4 MB, [s][d]
    u16*   kT   = (u16*)(ws + ((size_t)4 << 20));      //  4 MB, [d][t]
    u16*   vT   = (u16*)(ws + ((size_t)8 << 20));      //  4 MB, [e][t]
    // Wb (768 KB) aliases part (8 MB): Wb dead before kt_v writes part.
    u16*   Wb   = (u16*)(ws + ((size_t)12 << 20));
    float* part = (float*)(ws + ((size_t)12 << 20));
    u16*   T    = (u16*)(ws + ((size_t)20 << 20));     // 128 KB

    hipLaunchKernelGGL(wcvt, dim3(192), dim3(256), 0, stream, Wq, Wk, Wv, Wb);
    hipLaunchKernelGGL(qkv_fused, dim3(512), dim3(256), 0, stream,
                       x, Wb, bq, bk, bv, qo, kT, vT);
    hipLaunchKernelGGL(kt_v, dim3(32, 4), dim3(512), 0, stream, kT, vT, part);
    hipLaunchKernelGGL(reduceT, dim3(256), dim3(256), 0, stream, part, T);
    hipLaunchKernelGGL(out_gemm, dim3(512), dim3(256), 0, stream, qo, T, out);
}

// Round 8
// 148.320 us; speedup vs baseline: 1.1267x; 1.1267x over previous
//
#include <hip/hip_runtime.h>

typedef __bf16 bf16x8 __attribute__((ext_vector_type(8)));
typedef float f32x4 __attribute__((ext_vector_type(4)));
typedef unsigned short u16;
typedef unsigned short u16x4 __attribute__((ext_vector_type(4)));
typedef unsigned short u16x8 __attribute__((ext_vector_type(8)));

#define MFMA16(a, b, c) __builtin_amdgcn_mfma_f32_16x16x32_bf16(a, b, c, 0, 0, 0)

__device__ __forceinline__ u16 f2bf(float f) {
    unsigned u = __builtin_bit_cast(unsigned, f);
    u += 0x7fffu + ((u >> 16) & 1u);   // RNE
    return (u16)(u >> 16);
}

__device__ __forceinline__ bf16x8 ld_frag(const u16* p) {
    u16x8 v = *(const u16x8*)p;
    return __builtin_bit_cast(bf16x8, v);
}

__device__ __forceinline__ u16x8 pack8(float4 a, float4 b) {
    u16x8 o = { f2bf(a.x), f2bf(a.y), f2bf(a.z), f2bf(a.w),
                f2bf(b.x), f2bf(b.y), f2bf(b.z), f2bf(b.w) };
    return o;
}

// async global->LDS, 16B/lane; LDS dest = wave-uniform base + lane*16
__device__ __forceinline__ void glds16(const void* g, void* l) {
    __builtin_amdgcn_global_load_lds(
        (const __attribute__((address_space(1))) unsigned int*)g,
        (__attribute__((address_space(3))) unsigned int*)l, 16, 0, 0);
}

// ---------------------------------------------------------------------------
// wcvt: Wq|Wk|Wv fp32 -> Wb bf16, N-fused B-fragment order, BK=32 chunks.
// Wb u16 off = ((cc*24 + n16)*64 + lane)*8 ;  lane=(quad,l16), cc in 0..31
// element = Wcat[n16*16 + l16][cc*32 + quad*8 + j],  Wcat=[Wq;Wk;Wv]
// ---------------------------------------------------------------------------
__global__ __launch_bounds__(256) void wcvt(
    const float* __restrict__ Wq, const float* __restrict__ Wk,
    const float* __restrict__ Wv, u16* __restrict__ Wb)
{
    int g = blockIdx.x * 256 + threadIdx.x;   // 49152
    int lane = g & 63, l16 = g & 15, quad = (g >> 4) & 3;
    int n16 = (g >> 6) % 24;
    int cc  = (g >> 6) / 24;
    int nrow = n16 * 16 + l16;                // 0..383
    int nt = nrow >> 7, r = nrow & 127;
    int col = cc * 32 + quad * 8;
    const float* W = (nt == 0 ? Wq : nt == 1 ? Wk : Wv) + (size_t)r * 1024 + col;
    float4 a = *(const float4*)(W);
    float4 b = *(const float4*)(W + 4);
    (void)lane;
    *(u16x8*)(Wb + (size_t)g * 8) = pack8(a, b);
}

// ---------------------------------------------------------------------------
// qkv_fused: q|k|v = x @ W^T + b.  grid 256 (M-tile 64), 512 thr / 8 waves.
// N=384 fully fused (x read ONCE). BK=32, single-barrier double-buffered:
//   A: x fp32 coalesced read -> pack bf16 -> ds_write_b64 in frag order
//   B: 3x glds16/wave identity copy from frag-order Wb (L2-hot)
// Wave tile 32m x 96n: 2 A-frags, 6 B-frags, 12 MFMA16 per chunk.
// Epilogue reuses the LDS pool in 2 phases: q natural, then kT/vT [d][t].
// ---------------------------------------------------------------------------
__global__ __launch_bounds__(512, 2) void qkv_fused(
    const float* __restrict__ x, const u16* __restrict__ Wb,
    const float* __restrict__ bq, const float* __restrict__ bk,
    const float* __restrict__ bv,
    u16* __restrict__ qo, u16* __restrict__ kT, u16* __restrict__ vT)
{
    // pool 56 KB: A bufs [0..2047],[2048..4095]; B bufs [4096..16383],[16384..28671]
    __shared__ __align__(16) u16 smem[28672];

    const int m0 = blockIdx.x * 64;
    const int tid = threadIdx.x, lane = tid & 63, w = tid >> 6;
    const int quad = lane >> 4, l16 = lane & 15;
    const int wm32 = w & 1;          // m-half (32 rows)
    const int wn = (w >> 1) * 6;     // first n16 of this wave (6 x 16 = 96 cols)

    // A staging: thread -> (row arow, 4-float col seg ac4); wave reads 8 rows x 128B
    const int arow = tid >> 3, ac4 = tid & 7;
    const float* xp = x + (size_t)(m0 + arow) * 1024 + ac4 * 4;
    const int adst = (arow >> 4) * 512 + ((ac4 >> 1) * 16 + (arow & 15)) * 8 + (ac4 & 1) * 4;

    // B staging: wave w copies frags w*3..w*3+2 of each chunk
    const u16* wb0 = Wb + (w * 3) * 512 + lane * 8;

    f32x4 acc[2][6] = {};

    // prologue: chunk 0 -> buf 0
    #pragma unroll
    for (int j = 0; j < 3; ++j)
        glds16(wb0 + j * 512, &smem[4096 + (w * 3 + j) * 512]);
    {
        float4 xv = *(const float4*)(xp);
        u16x4 p = { f2bf(xv.x), f2bf(xv.y), f2bf(xv.z), f2bf(xv.w) };
        *(u16x4*)&smem[adst] = p;
    }

    for (int c = 0; c < 32; ++c) {
        const int cur = c & 1, nxt = cur ^ 1;
        __syncthreads();   // buf[cur] ready (glds16 drained by implicit vmcnt)

        float4 xv;
        if (c < 31) {      // prefetch chunk c+1 into buf[nxt] (read only after next barrier)
            const u16* wbn = wb0 + (size_t)(c + 1) * 12288;
            u16* Bn = &smem[4096 + nxt * 12288];
            #pragma unroll
            for (int j = 0; j < 3; ++j)
                glds16(wbn + j * 512, &Bn[(w * 3 + j) * 512]);
            xv = *(const float4*)(xp + (c + 1) * 32);
        }

        // compute chunk c (identity ds_read_b128, conflict-free)
        const u16* Ac = &smem[cur * 2048];
        const u16* Bc = &smem[4096 + cur * 12288];
        bf16x8 af[2], bfr[6];
        #pragma unroll
        for (int mi = 0; mi < 2; ++mi)
            af[mi] = ld_frag(&Ac[(wm32 * 2 + mi) * 512 + lane * 8]);
        #pragma unroll
        for (int ni = 0; ni < 6; ++ni)
            bfr[ni] = ld_frag(&Bc[(wn + ni) * 512 + lane * 8]);
        #pragma unroll
        for (int mi = 0; mi < 2; ++mi)
            #pragma unroll
            for (int ni = 0; ni < 6; ++ni)
                acc[mi][ni] = MFMA16(af[mi], bfr[ni], acc[mi][ni]);

        if (c < 31) {      // write A(c+1) into buf[nxt]
            u16x4 p = { f2bf(xv.x), f2bf(xv.y), f2bf(xv.z), f2bf(xv.w) };
            *(u16x4*)&smem[nxt * 2048 + adst] = p;
        }
    }

    // -------- epilogue, phase 1: q (n16g 0..7), Eq[64][136] --------
    __syncthreads();
    u16* Eq = smem;
    #pragma unroll
    for (int ni = 0; ni < 6; ++ni) {
        int n16g = wn + ni;
        if (n16g < 8) {
            int col = n16g * 16 + l16;
            float bb = bq[col];
            #pragma unroll
            for (int mi = 0; mi < 2; ++mi)
                #pragma unroll
                for (int r = 0; r < 4; ++r)
                    Eq[(wm32 * 32 + mi * 16 + quad * 4 + r) * 136 + col] =
                        f2bf(acc[mi][ni][r] + bb);
        }
    }
    __syncthreads();
    #pragma unroll
    for (int i = 0; i < 2; ++i) {
        int idx = tid + i * 512;                   // 0..1023
        int row = idx >> 4, d8 = (idx & 15) * 8;
        *(u16x8*)(qo + (size_t)(m0 + row) * 128 + d8) = *(u16x8*)&Eq[row * 136 + d8];
    }

    // -------- epilogue, phase 2: k,v transposed, Ek/Ev[128][72] --------
    __syncthreads();
    u16* Ek = smem;
    u16* Ev = smem + 9216;
    #pragma unroll
    for (int ni = 0; ni < 6; ++ni) {
        int n16g = wn + ni;
        if (n16g >= 8) {
            int col = (n16g & 7) * 16 + l16;       // d
            const float* bias = (n16g < 16) ? bk : bv;
            u16* E = (n16g < 16) ? Ek : Ev;
            float bb = bias[col];
            #pragma unroll
            for (int mi = 0; mi < 2; ++mi) {
                u16x4 v4 = { f2bf(acc[mi][ni][0] + bb), f2bf(acc[mi][ni][1] + bb),
                             f2bf(acc[mi][ni][2] + bb), f2bf(acc[mi][ni][3] + bb) };
                *(u16x4*)&E[col * 72 + wm32 * 32 + mi * 16 + quad * 4] = v4;
            }
        }
    }
    __syncthreads();
    #pragma unroll
    for (int i = 0; i < 2; ++i) {
        int idx = tid + i * 512;                   // 0..1023
        int d = idx >> 3, t8 = (idx & 7) * 8;
        *(u16x8*)(kT + (size_t)d * 16384 + m0 + t8) = *(u16x8*)&Ek[d * 72 + t8];
        *(u16x8*)(vT + (size_t)d * 16384 + m0 + t8) = *(u16x8*)&Ev[d * 72 + t8];
    }
}

// ---------------------------------------------------------------------------
// kt_v: partial T[e][d] = sum_t vT[e][t]*kT[d][t] over a 128-t chunk.
// grid (32,4), 512 threads / 8 waves (wave 64e x 32d).
// ---------------------------------------------------------------------------
__global__ __launch_bounds__(512) void kt_v(
    const u16* __restrict__ kT, const u16* __restrict__ vT,
    float* __restrict__ part)
{
    __shared__ __align__(16) u16 vL[128 * 136];
    __shared__ __align__(16) u16 kL[128 * 136];

    const int c = blockIdx.x, b = blockIdx.y;
    const size_t g0 = (size_t)b * 4096 + c * 128;
    const int tid = threadIdx.x, lane = tid & 63, w = tid >> 6;
    const int quad = lane >> 4, l16 = lane & 15;
    const int we = (w >> 2) * 64, wd = (w & 3) * 32;

    #pragma unroll
    for (int i = 0; i < 4; ++i) {
        int idx = tid + i * 512;
        int e = idx >> 4, t8 = (idx & 15) * 8;
        *(u16x8*)&vL[e * 136 + t8] = *(const u16x8*)(vT + (size_t)e * 16384 + g0 + t8);
        *(u16x8*)&kL[e * 136 + t8] = *(const u16x8*)(kT + (size_t)e * 16384 + g0 + t8);
    }
    __syncthreads();

    f32x4 acc[4][2] = {};
    #pragma unroll
    for (int ks = 0; ks < 4; ++ks) {
        bf16x8 af[4], bfr[2];
        #pragma unroll
        for (int mi = 0; mi < 4; ++mi)
            af[mi] = ld_frag(&vL[(we + mi * 16 + l16) * 136 + ks * 32 + quad * 8]);
        #pragma unroll
        for (int ni = 0; ni < 2; ++ni)
            bfr[ni] = ld_frag(&kL[(wd + ni * 16 + l16) * 136 + ks * 32 + quad * 8]);
        #pragma unroll
        for (int mi = 0; mi < 4; ++mi)
            #pragma unroll
            for (int ni = 0; ni < 2; ++ni)
                acc[mi][ni] = MFMA16(af[mi], bfr[ni], acc[mi][ni]);
    }

    float* dst = part + (size_t)(b * 32 + c) * 16384;
    #pragma unroll
    for (int mi = 0; mi < 4; ++mi)
        #pragma unroll
        for (int ni = 0; ni < 2; ++ni)
            #pragma unroll
            for (int r = 0; r < 4; ++r)
                dst[(we + mi * 16 + quad * 4 + r) * 128 + (wd + ni * 16 + l16)] =
                    acc[mi][ni][r];
}

// ---------------------------------------------------------------------------
// reduceT: 32 fp32 partials -> T bf16 [4][128][128], scale folded in.
// ---------------------------------------------------------------------------
__global__ __launch_bounds__(256) void reduceT(
    const float* __restrict__ part, u16* __restrict__ T)
{
    int gid = blockIdx.x * 256 + threadIdx.x;   // 0..65535
    int b = gid >> 14, idx = gid & 16383;
    const float* p = part + (size_t)b * 32 * 16384 + idx;
    float s = 0.f;
    #pragma unroll
    for (int c = 0; c < 32; ++c) s += p[(size_t)c * 16384];
    T[gid] = f2bf(s * 0.088388347648318447f);   // 128^-0.5
}

// ---------------------------------------------------------------------------
// out_gemm: outT-form — C[e][s], A=T[e][d], B=q[s][d] (both d-contig).
// C/D layout gives out[s][e] as contiguous f32x4 -> full-line stores.
// grid 512 (32-s tiles, 2 blocks/CU), 4 waves: wave 64e x 16s.
// ---------------------------------------------------------------------------
__global__ __launch_bounds__(256) void out_gemm(
    const u16* __restrict__ qo, const u16* __restrict__ T,
    float* __restrict__ out)
{
    __shared__ __align__(16) u16 tL[128 * 136];
    __shared__ __align__(16) u16 qL[32 * 136];

    const int s0 = blockIdx.x * 32;
    const int b  = s0 >> 12;
    const int tid = threadIdx.x, lane = tid & 63, w = tid >> 6;
    const int quad = lane >> 4, l16 = lane & 15;
    const int we = (w >> 1) * 64, wsx = (w & 1) * 16;

    #pragma unroll
    for (int i = 0; i < 8; ++i) {
        int idx = tid + i * 256;
        int e = idx >> 4, d8 = (idx & 15) * 8;
        *(u16x8*)&tL[e * 136 + d8] = *(const u16x8*)(T + (size_t)b * 16384 + e * 128 + d8);
    }
    #pragma unroll
    for (int i = 0; i < 2; ++i) {
        int idx = tid + i * 256;
        int sr = idx >> 4, d8 = (idx & 15) * 8;
        *(u16x8*)&qL[sr * 136 + d8] = *(const u16x8*)(qo + (size_t)(s0 + sr) * 128 + d8);
    }
    __syncthreads();

    f32x4 acc[4] = {};
    #pragma unroll
    for (int ks = 0; ks < 4; ++ks) {
        bf16x8 bfr = ld_frag(&qL[(wsx + l16) * 136 + ks * 32 + quad * 8]);
        #pragma unroll
        for (int mi = 0; mi < 4; ++mi) {
            bf16x8 af = ld_frag(&tL[(we + mi * 16 + l16) * 136 + ks * 32 + quad * 8]);
            acc[mi] = MFMA16(af, bfr, acc[mi]);
        }
    }

    #pragma unroll
    for (int mi = 0; mi < 4; ++mi) {
        int s = s0 + wsx + l16;
        int e0 = we + mi * 16 + quad * 4;
        *(f32x4*)(out + (size_t)s * 128 + e0) = acc[mi];
    }
}

// ---------------------------------------------------------------------------
extern "C" void kernel_launch(void* const* d_in, const int* in_sizes, int n_in,
                              void* d_out, int out_size, void* d_ws, size_t ws_size,
                              hipStream_t stream)
{
    const float* x  = (const float*)d_in[0];
    const float* Wq = (const float*)d_in[1];
    const float* bq = (const float*)d_in[2];
    const float* Wk = (const float*)d_in[3];
    const float* bk = (const float*)d_in[4];
    const float* Wv = (const float*)d_in[5];
    const float* bv = (const float*)d_in[6];
    float* out = (float*)d_out;

    char* ws = (char*)d_ws;
    u16*   qo   = (u16*)(ws);                          //  4 MB, [s][d]
    u16*   kT   = (u16*)(ws + ((size_t)4 << 20));      //  4 MB, [d][t]
    u16*   vT   = (u16*)(ws + ((size_t)8 << 20));      //  4 MB, [e][t]
    // Wb (768 KB) aliases part (8 MB): Wb dead before kt_v writes part.
    u16*   Wb   = (u16*)(ws + ((size_t)12 << 20));
    float* part = (float*)(ws + ((size_t)12 << 20));
    u16*   T    = (u16*)(ws + ((size_t)20 << 20));     // 128 KB

    hipLaunchKernelGGL(wcvt, dim3(192), dim3(256), 0, stream, Wq, Wk, Wv, Wb);
    hipLaunchKernelGGL(qkv_fused, dim3(256), dim3(512), 0, stream,
                       x, Wb, bq, bk, bv, qo, kT, vT);
    hipLaunchKernelGGL(kt_v, dim3(32, 4), dim3(512), 0, stream, kT, vT, part);
    hipLaunchKernelGGL(reduceT, dim3(256), dim3(256), 0, stream, part, T);
    hipLaunchKernelGGL(out_gemm, dim3(512), dim3(256), 0, stream, qo, T, out);
}